// Round 2
// baseline (442.625 us; speedup 1.0000x reference)
//
#include <hip/hip_runtime.h>
#include <cstdint>
#include <cstddef>

typedef unsigned short u16;
typedef __attribute__((ext_vector_type(8))) short short8;
typedef __attribute__((ext_vector_type(8))) u16 ushort8;
typedef __attribute__((ext_vector_type(4))) float float4_t;

#define BB 8
#define NN 8192
#define DD 64
#define NTILES 64            // 8192 / 128 column tiles (pre_kernel format)
#define TILE_SHORTS 8192     // 128 points * 64 k (bf16)
#define LDS_STRIDE 68        // 64 floats + 4 pad (bank spread)

__device__ inline u16 f32_to_bf16(float f) {
  unsigned u = __float_as_uint(f);
  u += 0x7FFFu + ((u >> 16) & 1u);   // RNE
  return (u16)(u >> 16);
}

__device__ inline unsigned enc_ord(float f) {
  unsigned u = __float_as_uint(f);
  return (u & 0x80000000u) ? ~u : (u | 0x80000000u);
}
__device__ inline float dec_ord(unsigned u) {
  return __uint_as_float((u & 0x80000000u) ? (u & 0x7fffffffu) : ~u);
}

// ---------------------------------------------------------------------------
// K1: one block = one 128x64 tile. Coalesced read-once -> LDS -> swizzled
// bf16 tile (MFMA fragment chunk order) + 0.5*|row|^2. Zeroes out[] and, in
// the fallback path, the ordered-uint max buffers.  [verified R6/R7 — UNCHANGED]
// Chunk layout per tile: [I(8)][s(2)] chunks of 1KB; within a chunk lane
// l (l=qq*16+rl) holds point I*16+rl, k = s*32+qq*8+j (j=0..7, 16B).
// ---------------------------------------------------------------------------
__global__ __launch_bounds__(256) void pre_kernel(
    const float* __restrict__ x, const float* __restrict__ y,
    u16* __restrict__ xs, u16* __restrict__ ys,
    float* __restrict__ x2h, float* __restrict__ y2h,
    unsigned* __restrict__ rowmax_u, unsigned* __restrict__ colmax_u,
    float* __restrict__ out, const int use_part)
{
  __shared__ float stage[128 * LDS_STRIDE];   // 34 KB

  const int bid = blockIdx.x;          // 1024: 0..511 -> x, 512..1023 -> y
  const int tid = threadIdx.x;

  if (!use_part) {
    if (bid < 256)      colmax_u[(bid << 8) | tid] = 0u;
    else if (bid < 512) rowmax_u[((bid - 256) << 8) | tid] = 0u;
  }
  if (bid == 0 && tid == 0) out[0] = 0.f;

  const bool isY = bid >= 512;
  const int t = bid & 511;             // tile id = b*64 + nt
  const float* src = (isY ? y : x) + (size_t)t * (128 * DD);
  u16* dst = (isY ? ys : xs) + (size_t)t * TILE_SHORTS;
  float* s2 = (isY ? y2h : x2h) + t * 128;

#pragma unroll
  for (int c = 0; c < 8; ++c) {
    const int idx = c * 256 + tid;     // float4 index within tile (0..2047)
    float4 f = ((const float4*)src)[idx];
    const int r = idx >> 4, kc = idx & 15;
    *(float4*)&stage[r * LDS_STRIDE + kc * 4] = f;
  }
  __syncthreads();

  {
    const int r = tid >> 1, half = tid & 1;
    const float* rp = &stage[r * LDS_STRIDE + half * 32];
    float ss = 0.f;
#pragma unroll
    for (int k = 0; k < 8; ++k) {
      float4 f = *(const float4*)&rp[k * 4];
      ss += f.x*f.x + f.y*f.y + f.z*f.z + f.w*f.w;
    }
    ss += __shfl_xor(ss, 1);
    if (half == 0) s2[r] = 0.5f * ss;
  }

  {
    const int w = tid >> 6, lane = tid & 63;
    const int qq = lane >> 4, rl = lane & 15;
#pragma unroll
    for (int u = 0; u < 4; ++u) {
      const int chunk = w * 4 + u;
      const int I = chunk >> 1, s = chunk & 1;
      const float* rp = &stage[(I*16 + rl) * LDS_STRIDE + s*32 + qq*8];
      ushort8 o;
#pragma unroll
      for (int j = 0; j < 8; ++j) o[j] = f32_to_bf16(rp[j]);
      *(ushort8*)(dst + chunk*512 + lane*8) = o;
    }
  }
}

// ---------------------------------------------------------------------------
// K2: main — R10. R9 post-mortem: 64-row tiles doubled colpart to 32 MiB >
// ws_size -> atomic fallback fired (WRITE_SIZE 127 MB = 2M cross-XCD
// atomicMax) -> 231 us. Occupancy thesis itself was confirmed (84 VGPR,
// 31% occ).  R10 keeps R0's EXACT I/O (grid 1024, 128-row tiles, colpart
// 16 MiB, need=33 MiB proven to fit) and fixes register pressure by
// splitting waves 2x2 over rows x cols instead of 1x4 over cols:
//   wave (wr,wc): rows wr*64..+63, cols wc*64..+63 of each col-tile.
// Per-wave state: afr[4][2]=32, negx2[4]=16, rowmax[4][4]=16, B[4][2]=32,
// acc[4]=16 live  ->  ~128 regs -> 4 waves/SIMD under launch_bounds(256,4)
// (R0 was ~200 regs spilling into AGPRs -> 2 waves/SIMD, MfmaUtil 33%).
// Cross-wave col combine (wr pair shares columns) is barrier-free via LDS
// ds_max_u32 on an ordered-uint colbuf[4096], drained once at kernel end
// (also replaces per-mt global colpart stores).
// R3/R4/R6/R8 bans respected: C-init carries -x2/2, jj-sequential acc.
// ---------------------------------------------------------------------------
__global__ __launch_bounds__(256, 4) void main_kernel(
    const u16* __restrict__ xs, const u16* __restrict__ ys,
    const float* __restrict__ x2h, const float* __restrict__ y2h,
    float* __restrict__ rowpart, float* __restrict__ colpart,
    unsigned* __restrict__ rowmax_u, unsigned* __restrict__ colmax_u,
    const int use_part)
{
  __shared__ unsigned colbuf[4096];    // 16 KB: 32 mt x 128 cols, enc_ord
  __shared__ float rowbuf[2][128];     // [wc][row]

  const int bid = blockIdx.x;            // 1024
  const int b   = bid & 7;               // XCD-affine
  const int nt  = (bid >> 3) & 63;
  const int h   = bid >> 9;              // column half
  const int tid = threadIdx.x;
  const int w = tid >> 6, lane = tid & 63;
  const int wr = w >> 1, wc = w & 1;     // row-half / col-half owner
  const int l15 = lane & 15, q = lane >> 4;
  const int n0 = nt << 7;
  const int mt_start = h << 5;           // 32 col-tiles per block

  // colbuf init: 0u is below every enc_ord of a finite float
#pragma unroll
  for (int k = 0; k < 16; ++k) colbuf[k * 256 + tid] = 0u;

  // ---- A fragments: this wave's 64 rows, both K-halves ----
  const u16* xs_tile = xs + (size_t)((b << 6) | nt) * TILE_SHORTS;
  short8 afr[4][2];
#pragma unroll
  for (int i = 0; i < 4; ++i)
#pragma unroll
    for (int s = 0; s < 2; ++s)
      afr[i][s] = *(const short8*)(xs_tile + ((wr*4 + i)*2 + s)*512 + lane*8);

  // ---- C-init quads: -x2/2 per row (fp32 exact) ----
  float4_t negx2[4];
  const float* x2b = x2h + b*NN + n0 + wr*64;
#pragma unroll
  for (int i = 0; i < 4; ++i) {
    float4_t v = *(const float4_t*)(x2b + i*16 + q*4);
    negx2[i] = {-v[0], -v[1], -v[2], -v[3]};
  }

  float rowmax[4][4];
#pragma unroll
  for (int i = 0; i < 4; ++i)
#pragma unroll
    for (int r = 0; r < 4; ++r) rowmax[i][r] = -3.0e38f;

  // ---- pointer-bumped streams; imm offsets cover the 8 chunk loads ----
  const u16*  pB = ys + (size_t)((b << 6) + mt_start) * TILE_SHORTS
                   + wc*4096 + lane*8;
  const float* pY = y2h + b*NN + mt_start*128 + wc*64 + l15;

  __syncthreads();                       // colbuf init visible to all waves

  int moff = 0;
  for (int mt = 0; mt < 32; ++mt) {
    // B fragments for this wave's 64-col slice (8 x dwordx4, imm offsets)
    short8 Bf[4][2];
#pragma unroll
    for (int jj = 0; jj < 4; ++jj)
#pragma unroll
      for (int s = 0; s < 2; ++s)
        Bf[jj][s] = *(const short8*)(pB + (jj*2 + s)*512);
    float y2v[4];
#pragma unroll
    for (int jj = 0; jj < 4; ++jj) y2v[jj] = pY[jj*16];

#pragma unroll
    for (int jj = 0; jj < 4; ++jj) {
      // acc = xy - x2/2 (C carries exact fp32 -x2/2); jj-sequential keeps
      // live accumulators at 4 x float4
      float4_t acc[4];
#pragma unroll
      for (int i = 0; i < 4; ++i)
        acc[i] = __builtin_amdgcn_mfma_f32_16x16x32_bf16(afr[i][0], Bf[jj][0], negx2[i], 0, 0, 0);
#pragma unroll
      for (int i = 0; i < 4; ++i)
        acc[i] = __builtin_amdgcn_mfma_f32_16x16x32_bf16(afr[i][1], Bf[jj][1], acc[i], 0, 0, 0);

      // col side: in-lane max over this wave's 16 row-slots, then fold the
      // q row-groups via shfl; one LDS atomic per column (q==0 lanes)
      float cm = fmaxf(fmaxf(acc[0][0], acc[0][1]), fmaxf(acc[0][2], acc[0][3]));
#pragma unroll
      for (int i = 1; i < 4; ++i)
        cm = fmaxf(fmaxf(cm, fmaxf(acc[i][0], acc[i][1])),
                   fmaxf(acc[i][2], acc[i][3]));
      cm = fmaxf(cm, __shfl_xor(cm, 16));
      cm = fmaxf(cm, __shfl_xor(cm, 32));
      if (q == 0)
        atomicMax(&colbuf[moff + wc*64 + jj*16 + l15], enc_ord(cm));

      // row side: rowmax = max(acc - y2/2) = -min(d^2)/2
      const float y2j = y2v[jj];
#pragma unroll
      for (int i = 0; i < 4; ++i)
#pragma unroll
        for (int r = 0; r < 4; ++r)
          rowmax[i][r] = fmaxf(rowmax[i][r], acc[i][r] - y2j);
    }

    pB += TILE_SHORTS;
    pY += 128;
    moff += 128;
  }

  // ---- row side finalize: shfl over cols (l15), cross-wc via LDS ----
#pragma unroll
  for (int i = 0; i < 4; ++i)
#pragma unroll
    for (int r = 0; r < 4; ++r) {
      float v = rowmax[i][r];
      v = fmaxf(v, __shfl_xor(v, 1));
      v = fmaxf(v, __shfl_xor(v, 2));
      v = fmaxf(v, __shfl_xor(v, 4));
      v = fmaxf(v, __shfl_xor(v, 8));
      rowmax[i][r] = v;
    }
  if (l15 == 0) {
#pragma unroll
    for (int i = 0; i < 4; ++i)
#pragma unroll
      for (int r = 0; r < 4; ++r)
        rowbuf[wc][wr*64 + i*16 + q*4 + r] = rowmax[i][r];
  }
  __syncthreads();

  if (tid < 128) {
    float v = fmaxf(rowbuf[0][tid], rowbuf[1][tid]);     // -min(d^2)/2
    if (use_part) rowpart[(size_t)((h << 9) | (b << 6) | nt) * 128 + tid] = v;
    else          atomicMax(&rowmax_u[b*NN + n0 + tid], enc_ord(v));
  }

  // ---- col drain: 16 KB coalesced (partial path) or 4096 global atomics ----
  {
    float*    colp = colpart + (size_t)((b << 6) | nt) * NN + (h << 12);
    unsigned* colu = colmax_u + b*NN + (h << 12);
#pragma unroll
    for (int k = 0; k < 16; ++k) {
      const int t = k * 256 + tid;
      const unsigned e = colbuf[t];
      if (use_part) colp[t] = dec_ord(e);
      else          atomicMax(&colu[t], e);
    }
  }
}

// ---------------------------------------------------------------------------
// K3: col combine over 64 nt + sqrt; row combine over 2 h + sqrt; block sum;
// atomicAdd scaled result into out.  [R0 version verbatim]
// ---------------------------------------------------------------------------
__global__ __launch_bounds__(256) void reduce_kernel(
    const float* __restrict__ rowpart, const float* __restrict__ colpart,
    const unsigned* __restrict__ rowmax_u, const unsigned* __restrict__ colmax_u,
    const float* __restrict__ y2h, float* __restrict__ out,
    const int use_part)
{
  const int bid = blockIdx.x;          // 256
  const int tid = threadIdx.x;
  const int g = bid*256 + tid;         // 0..65535
  const int b = g >> 13, m = g & (NN - 1);

  float vc, vr;
  if (use_part) {
    vc = -3.0e38f;
#pragma unroll 8
    for (int nt = 0; nt < 64; ++nt)
      vc = fmaxf(vc, colpart[(size_t)((b << 6) | nt) * NN + m]);
    const int nt = m >> 7, r = m & 127;
    float r0 = rowpart[(size_t)((0 << 9) | (b << 6) | nt) * 128 + r];
    float r1 = rowpart[(size_t)((1 << 9) | (b << 6) | nt) * 128 + r];
    vr = fmaxf(r0, r1);
  } else {
    vc = dec_ord(colmax_u[g]);
    vr = dec_ord(rowmax_u[g]);
  }
  float s = sqrtf(fmaxf(2.f*(y2h[g] - vc), 0.f))   // nearest-x for this y
          + sqrtf(fmaxf(-2.f*vr, 0.f));            // nearest-y for this x

#pragma unroll
  for (int d = 1; d < 64; d <<= 1) s += __shfl_xor(s, d);
  __shared__ float wsum[4];
  if ((tid & 63) == 0) wsum[tid >> 6] = s;
  __syncthreads();
  if (tid == 0)
    atomicAdd(out, (wsum[0] + wsum[1] + wsum[2] + wsum[3]) * (1.0f / 65536.0f));
}

// ---------------------------------------------------------------------------
extern "C" void kernel_launch(void* const* d_in, const int* in_sizes, int n_in,
                              void* d_out, int out_size, void* d_ws, size_t ws_size,
                              hipStream_t stream) {
  const float* x = (const float*)d_in[0];
  const float* y = (const float*)d_in[1];
  float* out = (float*)d_out;

  char* p = (char*)d_ws;
  u16* xs = (u16*)p;            p += (size_t)512 * 16384;   // 8 MiB
  u16* ys = (u16*)p;            p += (size_t)512 * 16384;   // 8 MiB
  float* x2h = (float*)p;       p += (size_t)65536 * 4;
  float* y2h = (float*)p;       p += (size_t)65536 * 4;
  char* tail = p;
  // partial path: colpart 16 MiB + rowpart 512 KiB  (33 MiB total — proven
  // to fit in R0; R9's 49 MiB overflowed and fell back to atomics)
  float* colpart = (float*)tail;
  float* rowpart = (float*)(tail + (size_t)512 * 8192 * 4);
  // atomic fallback: two 256 KiB ordered-uint max buffers
  unsigned* colmax_u = (unsigned*)tail;
  unsigned* rowmax_u = (unsigned*)(tail + (size_t)65536 * 4);
  const size_t need_part = (size_t)(tail - (char*)d_ws) +
                           (size_t)512 * 8192 * 4 + (size_t)1024 * 128 * 4;
  const int use_part = (ws_size >= need_part) ? 1 : 0;

  pre_kernel<<<dim3(1024), dim3(256), 0, stream>>>(x, y, xs, ys, x2h, y2h,
                                                   rowmax_u, colmax_u, out,
                                                   use_part);
  main_kernel<<<dim3(1024), dim3(256), 0, stream>>>(xs, ys, x2h, y2h,
                                                    rowpart, colpart,
                                                    rowmax_u, colmax_u,
                                                    use_part);
  reduce_kernel<<<dim3(256), dim3(256), 0, stream>>>(rowpart, colpart,
                                                     rowmax_u, colmax_u, y2h,
                                                     out, use_part);
}

// Round 3
// 179.881 us; speedup vs baseline: 2.4606x; 2.4606x over previous
//
#include <hip/hip_runtime.h>
#include <cstdint>
#include <cstddef>

typedef unsigned short u16;
typedef __attribute__((ext_vector_type(8))) short short8;
typedef __attribute__((ext_vector_type(8))) u16 ushort8;
typedef __attribute__((ext_vector_type(4))) float float4_t;

#define BB 8
#define NN 8192
#define DD 64
#define NTILES 64            // 8192 / 128 column tiles (pre_kernel format)
#define TILE_SHORTS 8192     // 128 points * 64 k (bf16)
#define LDS_STRIDE 68        // 64 floats + 4 pad (bank spread)

__device__ inline u16 f32_to_bf16(float f) {
  unsigned u = __float_as_uint(f);
  u += 0x7FFFu + ((u >> 16) & 1u);   // RNE
  return (u16)(u >> 16);
}

__device__ inline unsigned enc_ord(float f) {
  unsigned u = __float_as_uint(f);
  return (u & 0x80000000u) ? ~u : (u | 0x80000000u);
}
__device__ inline float dec_ord(unsigned u) {
  return __uint_as_float((u & 0x80000000u) ? (u & 0x7fffffffu) : ~u);
}

// ---------------------------------------------------------------------------
// K1: one block = one 128x64 tile. Coalesced read-once -> LDS -> swizzled
// bf16 tile (MFMA fragment chunk order) + 0.5*|row|^2. Zeroes out[] and, in
// the fallback path, the ordered-uint max buffers.  [verified R6/R7 — UNCHANGED]
// Chunk layout per tile: [I(8)][s(2)] chunks of 1KB; within a chunk lane
// l (l=qq*16+rl) holds point I*16+rl, k = s*32+qq*8+j (j=0..7, 16B).
// ---------------------------------------------------------------------------
__global__ __launch_bounds__(256) void pre_kernel(
    const float* __restrict__ x, const float* __restrict__ y,
    u16* __restrict__ xs, u16* __restrict__ ys,
    float* __restrict__ x2h, float* __restrict__ y2h,
    unsigned* __restrict__ rowmax_u, unsigned* __restrict__ colmax_u,
    float* __restrict__ out, const int use_part)
{
  __shared__ float stage[128 * LDS_STRIDE];   // 34 KB

  const int bid = blockIdx.x;          // 1024: 0..511 -> x, 512..1023 -> y
  const int tid = threadIdx.x;

  if (!use_part) {
    if (bid < 256)      colmax_u[(bid << 8) | tid] = 0u;
    else if (bid < 512) rowmax_u[((bid - 256) << 8) | tid] = 0u;
  }
  if (bid == 0 && tid == 0) out[0] = 0.f;

  const bool isY = bid >= 512;
  const int t = bid & 511;             // tile id = b*64 + nt
  const float* src = (isY ? y : x) + (size_t)t * (128 * DD);
  u16* dst = (isY ? ys : xs) + (size_t)t * TILE_SHORTS;
  float* s2 = (isY ? y2h : x2h) + t * 128;

#pragma unroll
  for (int c = 0; c < 8; ++c) {
    const int idx = c * 256 + tid;     // float4 index within tile (0..2047)
    float4 f = ((const float4*)src)[idx];
    const int r = idx >> 4, kc = idx & 15;
    *(float4*)&stage[r * LDS_STRIDE + kc * 4] = f;
  }
  __syncthreads();

  {
    const int r = tid >> 1, half = tid & 1;
    const float* rp = &stage[r * LDS_STRIDE + half * 32];
    float ss = 0.f;
#pragma unroll
    for (int k = 0; k < 8; ++k) {
      float4 f = *(const float4*)&rp[k * 4];
      ss += f.x*f.x + f.y*f.y + f.z*f.z + f.w*f.w;
    }
    ss += __shfl_xor(ss, 1);
    if (half == 0) s2[r] = 0.5f * ss;
  }

  {
    const int w = tid >> 6, lane = tid & 63;
    const int qq = lane >> 4, rl = lane & 15;
#pragma unroll
    for (int u = 0; u < 4; ++u) {
      const int chunk = w * 4 + u;
      const int I = chunk >> 1, s = chunk & 1;
      const float* rp = &stage[(I*16 + rl) * LDS_STRIDE + s*32 + qq*8];
      ushort8 o;
#pragma unroll
      for (int j = 0; j < 8; ++j) o[j] = f32_to_bf16(rp[j]);
      *(ushort8*)(dst + chunk*512 + lane*8) = o;
    }
  }
}

// ---------------------------------------------------------------------------
// K2: main — R11.  R10 post-mortem: launch_bounds(256,4) capped the
// allocator at 128 unified regs for a ~130-reg state -> scratch spills
// (VGPR_Count 64, WRITE_SIZE 243 MB = partials + 230 MB scratch) -> 378 us.
// The 2x2 wave-split index math itself PASSED correctness in R10.
// R11 keeps R0's exact geometry (grid 1024 = h|nt|b, 128-row tiles,
// colpart 16 MiB — need 33 MiB, proven to fit) and R10's 2x2 wave split,
// with three fixes:
//   1. launch_bounds(256,3) — R9 proved this compiles a same-size state
//      with 84 VGPR and no spills; 3 blocks/CU = 12 waves/CU.
//   2. No LDS atomics: colbuf[2][4096] float planes, one per wr. Every
//      slot [wr][mt*128 + wc*64 + jj*16 + l15] is written by exactly one
//      q==0 lane of wave (wr,wc) -> plain ds_write, no init, ZERO in-loop
//      barriers; one __syncthreads before the drain folds the two planes.
//   3. Col drain writes R0-shaped colpart slabs (or enc_ord atomics in
//      the fallback path).
// R3/R4/R6/R8 bans respected: C-init carries -x2/2, jj-sequential acc.
// ---------------------------------------------------------------------------
__global__ __launch_bounds__(256, 3) void main_kernel(
    const u16* __restrict__ xs, const u16* __restrict__ ys,
    const float* __restrict__ x2h, const float* __restrict__ y2h,
    float* __restrict__ rowpart, float* __restrict__ colpart,
    unsigned* __restrict__ rowmax_u, unsigned* __restrict__ colmax_u,
    const int use_part)
{
  __shared__ float colbuf[2][4096];    // 32 KB: [wr][mt*128 + col]
  __shared__ float rowbuf[2][128];     // [wc][row]

  const int bid = blockIdx.x;            // 1024
  const int b   = bid & 7;               // XCD-affine
  const int nt  = (bid >> 3) & 63;
  const int h   = bid >> 9;              // column half
  const int tid = threadIdx.x;
  const int w = tid >> 6, lane = tid & 63;
  const int wr = w >> 1, wc = w & 1;     // row-half / col-half owner
  const int l15 = lane & 15, q = lane >> 4;
  const int n0 = nt << 7;
  const int mt_start = h << 5;           // 32 col-tiles per block

  // ---- A fragments: this wave's 64 rows, both K-halves ----
  const u16* xs_tile = xs + (size_t)((b << 6) | nt) * TILE_SHORTS;
  short8 afr[4][2];
#pragma unroll
  for (int i = 0; i < 4; ++i)
#pragma unroll
    for (int s = 0; s < 2; ++s)
      afr[i][s] = *(const short8*)(xs_tile + ((wr*4 + i)*2 + s)*512 + lane*8);

  // ---- C-init quads: -x2/2 per row (fp32 exact) ----
  float4_t negx2[4];
  const float* x2b = x2h + b*NN + n0 + wr*64;
#pragma unroll
  for (int i = 0; i < 4; ++i) {
    float4_t v = *(const float4_t*)(x2b + i*16 + q*4);
    negx2[i] = {-v[0], -v[1], -v[2], -v[3]};
  }

  float rowmax[4][4];
#pragma unroll
  for (int i = 0; i < 4; ++i)
#pragma unroll
    for (int r = 0; r < 4; ++r) rowmax[i][r] = -3.0e38f;

  // ---- pointer-bumped streams; imm offsets cover the 8 chunk loads ----
  const u16*  pB = ys + (size_t)((b << 6) + mt_start) * TILE_SHORTS
                   + wc*4096 + lane*8;
  const float* pY = y2h + b*NN + mt_start*128 + wc*64 + l15;

  int moff = 0;
  for (int mt = 0; mt < 32; ++mt) {
    // B fragments for this wave's 64-col slice (8 x dwordx4, imm offsets)
    short8 Bf[4][2];
#pragma unroll
    for (int jj = 0; jj < 4; ++jj)
#pragma unroll
      for (int s = 0; s < 2; ++s)
        Bf[jj][s] = *(const short8*)(pB + (jj*2 + s)*512);
    float y2v[4];
#pragma unroll
    for (int jj = 0; jj < 4; ++jj) y2v[jj] = pY[jj*16];

#pragma unroll
    for (int jj = 0; jj < 4; ++jj) {
      // acc = xy - x2/2 (C carries exact fp32 -x2/2); jj-sequential keeps
      // live accumulators at 4 x float4
      float4_t acc[4];
#pragma unroll
      for (int i = 0; i < 4; ++i)
        acc[i] = __builtin_amdgcn_mfma_f32_16x16x32_bf16(afr[i][0], Bf[jj][0], negx2[i], 0, 0, 0);
#pragma unroll
      for (int i = 0; i < 4; ++i)
        acc[i] = __builtin_amdgcn_mfma_f32_16x16x32_bf16(afr[i][1], Bf[jj][1], acc[i], 0, 0, 0);

      // col side: in-lane max over this wave's 16 row-slots, then fold the
      // q row-groups via shfl; one plain ds_write per column (q==0 lanes)
      float cm = fmaxf(fmaxf(acc[0][0], acc[0][1]), fmaxf(acc[0][2], acc[0][3]));
#pragma unroll
      for (int i = 1; i < 4; ++i)
        cm = fmaxf(fmaxf(cm, fmaxf(acc[i][0], acc[i][1])),
                   fmaxf(acc[i][2], acc[i][3]));
      cm = fmaxf(cm, __shfl_xor(cm, 16));
      cm = fmaxf(cm, __shfl_xor(cm, 32));
      if (q == 0)
        colbuf[wr][moff + wc*64 + jj*16 + l15] = cm;

      // row side: rowmax = max(acc - y2/2) = -min(d^2)/2
      const float y2j = y2v[jj];
#pragma unroll
      for (int i = 0; i < 4; ++i)
#pragma unroll
        for (int r = 0; r < 4; ++r)
          rowmax[i][r] = fmaxf(rowmax[i][r], acc[i][r] - y2j);
    }

    pB += TILE_SHORTS;
    pY += 128;
    moff += 128;
  }

  // ---- row side finalize: shfl over cols (l15), cross-wc via LDS ----
#pragma unroll
  for (int i = 0; i < 4; ++i)
#pragma unroll
    for (int r = 0; r < 4; ++r) {
      float v = rowmax[i][r];
      v = fmaxf(v, __shfl_xor(v, 1));
      v = fmaxf(v, __shfl_xor(v, 2));
      v = fmaxf(v, __shfl_xor(v, 4));
      v = fmaxf(v, __shfl_xor(v, 8));
      rowmax[i][r] = v;
    }
  if (l15 == 0) {
#pragma unroll
    for (int i = 0; i < 4; ++i)
#pragma unroll
      for (int r = 0; r < 4; ++r)
        rowbuf[wc][wr*64 + i*16 + q*4 + r] = rowmax[i][r];
  }
  __syncthreads();   // colbuf planes + rowbuf complete

  if (tid < 128) {
    float v = fmaxf(rowbuf[0][tid], rowbuf[1][tid]);     // -min(d^2)/2
    if (use_part) rowpart[(size_t)((h << 9) | (b << 6) | nt) * 128 + tid] = v;
    else          atomicMax(&rowmax_u[b*NN + n0 + tid], enc_ord(v));
  }

  // ---- col drain: fold wr planes; 16 KB coalesced stores (partial path) ----
  {
    float*    colp = colpart + (size_t)((b << 6) | nt) * NN + (h << 12);
    unsigned* colu = colmax_u + b*NN + (h << 12);
#pragma unroll
    for (int k = 0; k < 16; ++k) {
      const int t = k * 256 + tid;
      const float m = fmaxf(colbuf[0][t], colbuf[1][t]);
      if (use_part) colp[t] = m;
      else          atomicMax(&colu[t], enc_ord(m));
    }
  }
}

// ---------------------------------------------------------------------------
// K3: col combine over 64 nt + sqrt; row combine over 2 h + sqrt; block sum;
// atomicAdd scaled result into out.  [R0 version verbatim]
// ---------------------------------------------------------------------------
__global__ __launch_bounds__(256) void reduce_kernel(
    const float* __restrict__ rowpart, const float* __restrict__ colpart,
    const unsigned* __restrict__ rowmax_u, const unsigned* __restrict__ colmax_u,
    const float* __restrict__ y2h, float* __restrict__ out,
    const int use_part)
{
  const int bid = blockIdx.x;          // 256
  const int tid = threadIdx.x;
  const int g = bid*256 + tid;         // 0..65535
  const int b = g >> 13, m = g & (NN - 1);

  float vc, vr;
  if (use_part) {
    vc = -3.0e38f;
#pragma unroll 8
    for (int nt = 0; nt < 64; ++nt)
      vc = fmaxf(vc, colpart[(size_t)((b << 6) | nt) * NN + m]);
    const int nt = m >> 7, r = m & 127;
    float r0 = rowpart[(size_t)((0 << 9) | (b << 6) | nt) * 128 + r];
    float r1 = rowpart[(size_t)((1 << 9) | (b << 6) | nt) * 128 + r];
    vr = fmaxf(r0, r1);
  } else {
    vc = dec_ord(colmax_u[g]);
    vr = dec_ord(rowmax_u[g]);
  }
  float s = sqrtf(fmaxf(2.f*(y2h[g] - vc), 0.f))   // nearest-x for this y
          + sqrtf(fmaxf(-2.f*vr, 0.f));            // nearest-y for this x

#pragma unroll
  for (int d = 1; d < 64; d <<= 1) s += __shfl_xor(s, d);
  __shared__ float wsum[4];
  if ((tid & 63) == 0) wsum[tid >> 6] = s;
  __syncthreads();
  if (tid == 0)
    atomicAdd(out, (wsum[0] + wsum[1] + wsum[2] + wsum[3]) * (1.0f / 65536.0f));
}

// ---------------------------------------------------------------------------
extern "C" void kernel_launch(void* const* d_in, const int* in_sizes, int n_in,
                              void* d_out, int out_size, void* d_ws, size_t ws_size,
                              hipStream_t stream) {
  const float* x = (const float*)d_in[0];
  const float* y = (const float*)d_in[1];
  float* out = (float*)d_out;

  char* p = (char*)d_ws;
  u16* xs = (u16*)p;            p += (size_t)512 * 16384;   // 8 MiB
  u16* ys = (u16*)p;            p += (size_t)512 * 16384;   // 8 MiB
  float* x2h = (float*)p;       p += (size_t)65536 * 4;
  float* y2h = (float*)p;       p += (size_t)65536 * 4;
  char* tail = p;
  // partial path: colpart 16 MiB + rowpart 512 KiB  (33 MiB total — proven
  // to fit in R0; R9's 49 MiB overflowed and fell back to atomics)
  float* colpart = (float*)tail;
  float* rowpart = (float*)(tail + (size_t)512 * 8192 * 4);
  // atomic fallback: two 256 KiB ordered-uint max buffers
  unsigned* colmax_u = (unsigned*)tail;
  unsigned* rowmax_u = (unsigned*)(tail + (size_t)65536 * 4);
  const size_t need_part = (size_t)(tail - (char*)d_ws) +
                           (size_t)512 * 8192 * 4 + (size_t)1024 * 128 * 4;
  const int use_part = (ws_size >= need_part) ? 1 : 0;

  pre_kernel<<<dim3(1024), dim3(256), 0, stream>>>(x, y, xs, ys, x2h, y2h,
                                                   rowmax_u, colmax_u, out,
                                                   use_part);
  main_kernel<<<dim3(1024), dim3(256), 0, stream>>>(xs, ys, x2h, y2h,
                                                    rowpart, colpart,
                                                    rowmax_u, colmax_u,
                                                    use_part);
  reduce_kernel<<<dim3(256), dim3(256), 0, stream>>>(rowpart, colpart,
                                                     rowmax_u, colmax_u, y2h,
                                                     out, use_part);
}

// Round 4
// 177.964 us; speedup vs baseline: 2.4872x; 1.0108x over previous
//
#include <hip/hip_runtime.h>
#include <cstdint>
#include <cstddef>

typedef unsigned short u16;
typedef __attribute__((ext_vector_type(8))) short short8;
typedef __attribute__((ext_vector_type(8))) u16 ushort8;
typedef __attribute__((ext_vector_type(4))) float float4_t;

#define BB 8
#define NN 8192
#define DD 64
#define NTILES 64            // 8192 / 128 column tiles (pre_kernel format)
#define TILE_SHORTS 8192     // 128 points * 64 k (bf16)
#define LDS_STRIDE 68        // 64 floats + 4 pad (bank spread)

__device__ inline u16 f32_to_bf16(float f) {
  unsigned u = __float_as_uint(f);
  u += 0x7FFFu + ((u >> 16) & 1u);   // RNE
  return (u16)(u >> 16);
}

__device__ inline unsigned enc_ord(float f) {
  unsigned u = __float_as_uint(f);
  return (u & 0x80000000u) ? ~u : (u | 0x80000000u);
}
__device__ inline float dec_ord(unsigned u) {
  return __uint_as_float((u & 0x80000000u) ? (u & 0x7fffffffu) : ~u);
}

// ---------------------------------------------------------------------------
// K1: one block = one 128x64 tile. Coalesced read-once -> LDS -> swizzled
// bf16 tile (MFMA fragment chunk order) + 0.5*|row|^2. Zeroes out[] and, in
// the fallback path, the ordered-uint max buffers.  [verified R6/R7 — UNCHANGED]
// Chunk layout per tile: [I(8)][s(2)] chunks of 1KB; within a chunk lane
// l (l=qq*16+rl) holds point I*16+rl, k = s*32+qq*8+j (j=0..7, 16B).
// ---------------------------------------------------------------------------
__global__ __launch_bounds__(256) void pre_kernel(
    const float* __restrict__ x, const float* __restrict__ y,
    u16* __restrict__ xs, u16* __restrict__ ys,
    float* __restrict__ x2h, float* __restrict__ y2h,
    unsigned* __restrict__ rowmax_u, unsigned* __restrict__ colmax_u,
    float* __restrict__ out, const int use_part)
{
  __shared__ float stage[128 * LDS_STRIDE];   // 34 KB

  const int bid = blockIdx.x;          // 1024: 0..511 -> x, 512..1023 -> y
  const int tid = threadIdx.x;

  if (!use_part) {
    if (bid < 256)      colmax_u[(bid << 8) | tid] = 0u;
    else if (bid < 512) rowmax_u[((bid - 256) << 8) | tid] = 0u;
  }
  if (bid == 0 && tid == 0) out[0] = 0.f;

  const bool isY = bid >= 512;
  const int t = bid & 511;             // tile id = b*64 + nt
  const float* src = (isY ? y : x) + (size_t)t * (128 * DD);
  u16* dst = (isY ? ys : xs) + (size_t)t * TILE_SHORTS;
  float* s2 = (isY ? y2h : x2h) + t * 128;

#pragma unroll
  for (int c = 0; c < 8; ++c) {
    const int idx = c * 256 + tid;     // float4 index within tile (0..2047)
    float4 f = ((const float4*)src)[idx];
    const int r = idx >> 4, kc = idx & 15;
    *(float4*)&stage[r * LDS_STRIDE + kc * 4] = f;
  }
  __syncthreads();

  {
    const int r = tid >> 1, half = tid & 1;
    const float* rp = &stage[r * LDS_STRIDE + half * 32];
    float ss = 0.f;
#pragma unroll
    for (int k = 0; k < 8; ++k) {
      float4 f = *(const float4*)&rp[k * 4];
      ss += f.x*f.x + f.y*f.y + f.z*f.z + f.w*f.w;
    }
    ss += __shfl_xor(ss, 1);
    if (half == 0) s2[r] = 0.5f * ss;
  }

  {
    const int w = tid >> 6, lane = tid & 63;
    const int qq = lane >> 4, rl = lane & 15;
#pragma unroll
    for (int u = 0; u < 4; ++u) {
      const int chunk = w * 4 + u;
      const int I = chunk >> 1, s = chunk & 1;
      const float* rp = &stage[(I*16 + rl) * LDS_STRIDE + s*32 + qq*8];
      ushort8 o;
#pragma unroll
      for (int j = 0; j < 8; ++j) o[j] = f32_to_bf16(rp[j]);
      *(ushort8*)(dst + chunk*512 + lane*8) = o;
    }
  }
}

// ---------------------------------------------------------------------------
// K2: main — R12.  R11 post-mortem: removing the B prefetch put a full
// vmcnt stall (~250 cyc, L2-resident ys) on the critical path once per mt
// -> both MfmaUtil (33->27) and VALUBusy (62->56) dropped, 90->105 us.
// R12 = R11 verbatim (geometry/col planes/drain all correctness-proven)
// + jj-granular PING-PONG PREFETCH: while computing fragment-pair jj,
// issue loads for jj+1 (crossing into the next mt tile at jj=3).
// Issue-to-use distance ~= 8 MFMA + reduction VALU ~= L2 latency.
// Only +18 VGPR (2 x {short8x2 + y2}) vs R0's full-tile dbuf that cost
// ~200 regs -> peak ~130 regs, fits launch_bounds(256,3)'s 170 budget.
// Final prefetch of the last iteration reads <=512B past ys/y2h into
// mapped workspace and is never consumed — safe.
// R3/R4/R6/R8 bans respected: C-init carries -x2/2, jj-sequential acc.
// ---------------------------------------------------------------------------
__global__ __launch_bounds__(256, 3) void main_kernel(
    const u16* __restrict__ xs, const u16* __restrict__ ys,
    const float* __restrict__ x2h, const float* __restrict__ y2h,
    float* __restrict__ rowpart, float* __restrict__ colpart,
    unsigned* __restrict__ rowmax_u, unsigned* __restrict__ colmax_u,
    const int use_part)
{
  __shared__ float colbuf[2][4096];    // 32 KB: [wr][mt*128 + col]
  __shared__ float rowbuf[2][128];     // [wc][row]

  const int bid = blockIdx.x;            // 1024
  const int b   = bid & 7;               // XCD-affine
  const int nt  = (bid >> 3) & 63;
  const int h   = bid >> 9;              // column half
  const int tid = threadIdx.x;
  const int w = tid >> 6, lane = tid & 63;
  const int wr = w >> 1, wc = w & 1;     // row-half / col-half owner
  const int l15 = lane & 15, q = lane >> 4;
  const int n0 = nt << 7;
  const int mt_start = h << 5;           // 32 col-tiles per block

  // ---- A fragments: this wave's 64 rows, both K-halves ----
  const u16* xs_tile = xs + (size_t)((b << 6) | nt) * TILE_SHORTS;
  short8 afr[4][2];
#pragma unroll
  for (int i = 0; i < 4; ++i)
#pragma unroll
    for (int s = 0; s < 2; ++s)
      afr[i][s] = *(const short8*)(xs_tile + ((wr*4 + i)*2 + s)*512 + lane*8);

  // ---- C-init quads: -x2/2 per row (fp32 exact) ----
  float4_t negx2[4];
  const float* x2b = x2h + b*NN + n0 + wr*64;
#pragma unroll
  for (int i = 0; i < 4; ++i) {
    float4_t v = *(const float4_t*)(x2b + i*16 + q*4);
    negx2[i] = {-v[0], -v[1], -v[2], -v[3]};
  }

  float rowmax[4][4];
#pragma unroll
  for (int i = 0; i < 4; ++i)
#pragma unroll
    for (int r = 0; r < 4; ++r) rowmax[i][r] = -3.0e38f;

  // ---- pointer-bumped streams; imm offsets cover the chunk loads ----
  const u16*  pB = ys + (size_t)((b << 6) + mt_start) * TILE_SHORTS
                   + wc*4096 + lane*8;
  const float* pY = y2h + b*NN + mt_start*128 + wc*64 + l15;

  // ---- ping-pong B pipeline: prologue fills buffer A (mt=0, jj=0) ----
  short8 bA0, bA1, bB0, bB1;
  float  y2A, y2B;
  bA0 = *(const short8*)(pB);
  bA1 = *(const short8*)(pB + 512);
  y2A = pY[0];

  int moff = 0;
  for (int mt = 0; mt < 32; ++mt) {
    // STEP(JJ): compute with (C0,C1,YC) = fragment-pair JJ of tile mt,
    // prefetch (N0,N1,YN) = the NEXT fragment pair (next tile at JJ=3).
#define CHAM_STEP(JJ, NOFF, NY, C0, C1, YC, N0, N1, YN)                       \
    {                                                                         \
      N0 = *(const short8*)(pB + (NOFF));                                     \
      N1 = *(const short8*)(pB + (NOFF) + 512);                               \
      YN = pY[(NY)];                                                          \
      /* acc = xy - x2/2 (C carries exact fp32 -x2/2) */                      \
      float4_t acc[4];                                                        \
      acc[0] = __builtin_amdgcn_mfma_f32_16x16x32_bf16(afr[0][0], C0, negx2[0], 0, 0, 0); \
      acc[1] = __builtin_amdgcn_mfma_f32_16x16x32_bf16(afr[1][0], C0, negx2[1], 0, 0, 0); \
      acc[2] = __builtin_amdgcn_mfma_f32_16x16x32_bf16(afr[2][0], C0, negx2[2], 0, 0, 0); \
      acc[3] = __builtin_amdgcn_mfma_f32_16x16x32_bf16(afr[3][0], C0, negx2[3], 0, 0, 0); \
      acc[0] = __builtin_amdgcn_mfma_f32_16x16x32_bf16(afr[0][1], C1, acc[0], 0, 0, 0);   \
      acc[1] = __builtin_amdgcn_mfma_f32_16x16x32_bf16(afr[1][1], C1, acc[1], 0, 0, 0);   \
      acc[2] = __builtin_amdgcn_mfma_f32_16x16x32_bf16(afr[2][1], C1, acc[2], 0, 0, 0);   \
      acc[3] = __builtin_amdgcn_mfma_f32_16x16x32_bf16(afr[3][1], C1, acc[3], 0, 0, 0);   \
      /* col side: in-lane max over 16 row-slots, fold q via shfl */          \
      float cm = fmaxf(fmaxf(acc[0][0], acc[0][1]), fmaxf(acc[0][2], acc[0][3])); \
      cm = fmaxf(fmaxf(cm, fmaxf(acc[1][0], acc[1][1])), fmaxf(acc[1][2], acc[1][3])); \
      cm = fmaxf(fmaxf(cm, fmaxf(acc[2][0], acc[2][1])), fmaxf(acc[2][2], acc[2][3])); \
      cm = fmaxf(fmaxf(cm, fmaxf(acc[3][0], acc[3][1])), fmaxf(acc[3][2], acc[3][3])); \
      cm = fmaxf(cm, __shfl_xor(cm, 16));                                     \
      cm = fmaxf(cm, __shfl_xor(cm, 32));                                     \
      if (q == 0)                                                             \
        colbuf[wr][moff + wc*64 + (JJ)*16 + l15] = cm;                        \
      /* row side: rowmax = max(acc - y2/2) = -min(d^2)/2 */                  \
      {                                                                       \
        const float y2j = YC;                                                 \
        for (int i_ = 0; i_ < 4; ++i_)                                        \
          for (int r_ = 0; r_ < 4; ++r_)                                      \
            rowmax[i_][r_] = fmaxf(rowmax[i_][r_], acc[i_][r_] - y2j);        \
      }                                                                       \
    }
    CHAM_STEP(0, 1024,        16,  bA0, bA1, y2A, bB0, bB1, y2B)
    CHAM_STEP(1, 2048,        32,  bB0, bB1, y2B, bA0, bA1, y2A)
    CHAM_STEP(2, 3072,        48,  bA0, bA1, y2A, bB0, bB1, y2B)
    CHAM_STEP(3, TILE_SHORTS, 128, bB0, bB1, y2B, bA0, bA1, y2A)
#undef CHAM_STEP
    pB += TILE_SHORTS;
    pY += 128;
    moff += 128;
  }

  // ---- row side finalize: shfl over cols (l15), cross-wc via LDS ----
#pragma unroll
  for (int i = 0; i < 4; ++i)
#pragma unroll
    for (int r = 0; r < 4; ++r) {
      float v = rowmax[i][r];
      v = fmaxf(v, __shfl_xor(v, 1));
      v = fmaxf(v, __shfl_xor(v, 2));
      v = fmaxf(v, __shfl_xor(v, 4));
      v = fmaxf(v, __shfl_xor(v, 8));
      rowmax[i][r] = v;
    }
  if (l15 == 0) {
#pragma unroll
    for (int i = 0; i < 4; ++i)
#pragma unroll
      for (int r = 0; r < 4; ++r)
        rowbuf[wc][wr*64 + i*16 + q*4 + r] = rowmax[i][r];
  }
  __syncthreads();   // colbuf planes + rowbuf complete

  if (tid < 128) {
    float v = fmaxf(rowbuf[0][tid], rowbuf[1][tid]);     // -min(d^2)/2
    if (use_part) rowpart[(size_t)((h << 9) | (b << 6) | nt) * 128 + tid] = v;
    else          atomicMax(&rowmax_u[b*NN + n0 + tid], enc_ord(v));
  }

  // ---- col drain: fold wr planes; 16 KB coalesced stores (partial path) ----
  {
    float*    colp = colpart + (size_t)((b << 6) | nt) * NN + (h << 12);
    unsigned* colu = colmax_u + b*NN + (h << 12);
#pragma unroll
    for (int k = 0; k < 16; ++k) {
      const int t = k * 256 + tid;
      const float m = fmaxf(colbuf[0][t], colbuf[1][t]);
      if (use_part) colp[t] = m;
      else          atomicMax(&colu[t], enc_ord(m));
    }
  }
}

// ---------------------------------------------------------------------------
// K3: col combine over 64 nt + sqrt; row combine over 2 h + sqrt; block sum;
// atomicAdd scaled result into out.  [R0 version verbatim]
// ---------------------------------------------------------------------------
__global__ __launch_bounds__(256) void reduce_kernel(
    const float* __restrict__ rowpart, const float* __restrict__ colpart,
    const unsigned* __restrict__ rowmax_u, const unsigned* __restrict__ colmax_u,
    const float* __restrict__ y2h, float* __restrict__ out,
    const int use_part)
{
  const int bid = blockIdx.x;          // 256
  const int tid = threadIdx.x;
  const int g = bid*256 + tid;         // 0..65535
  const int b = g >> 13, m = g & (NN - 1);

  float vc, vr;
  if (use_part) {
    vc = -3.0e38f;
#pragma unroll 8
    for (int nt = 0; nt < 64; ++nt)
      vc = fmaxf(vc, colpart[(size_t)((b << 6) | nt) * NN + m]);
    const int nt = m >> 7, r = m & 127;
    float r0 = rowpart[(size_t)((0 << 9) | (b << 6) | nt) * 128 + r];
    float r1 = rowpart[(size_t)((1 << 9) | (b << 6) | nt) * 128 + r];
    vr = fmaxf(r0, r1);
  } else {
    vc = dec_ord(colmax_u[g]);
    vr = dec_ord(rowmax_u[g]);
  }
  float s = sqrtf(fmaxf(2.f*(y2h[g] - vc), 0.f))   // nearest-x for this y
          + sqrtf(fmaxf(-2.f*vr, 0.f));            // nearest-y for this x

#pragma unroll
  for (int d = 1; d < 64; d <<= 1) s += __shfl_xor(s, d);
  __shared__ float wsum[4];
  if ((tid & 63) == 0) wsum[tid >> 6] = s;
  __syncthreads();
  if (tid == 0)
    atomicAdd(out, (wsum[0] + wsum[1] + wsum[2] + wsum[3]) * (1.0f / 65536.0f));
}

// ---------------------------------------------------------------------------
extern "C" void kernel_launch(void* const* d_in, const int* in_sizes, int n_in,
                              void* d_out, int out_size, void* d_ws, size_t ws_size,
                              hipStream_t stream) {
  const float* x = (const float*)d_in[0];
  const float* y = (const float*)d_in[1];
  float* out = (float*)d_out;

  char* p = (char*)d_ws;
  u16* xs = (u16*)p;            p += (size_t)512 * 16384;   // 8 MiB
  u16* ys = (u16*)p;            p += (size_t)512 * 16384;   // 8 MiB
  float* x2h = (float*)p;       p += (size_t)65536 * 4;
  float* y2h = (float*)p;       p += (size_t)65536 * 4;
  char* tail = p;
  // partial path: colpart 16 MiB + rowpart 512 KiB  (33 MiB total — proven
  // to fit in R0; R9's 49 MiB overflowed and fell back to atomics)
  float* colpart = (float*)tail;
  float* rowpart = (float*)(tail + (size_t)512 * 8192 * 4);
  // atomic fallback: two 256 KiB ordered-uint max buffers
  unsigned* colmax_u = (unsigned*)tail;
  unsigned* rowmax_u = (unsigned*)(tail + (size_t)65536 * 4);
  const size_t need_part = (size_t)(tail - (char*)d_ws) +
                           (size_t)512 * 8192 * 4 + (size_t)1024 * 128 * 4;
  const int use_part = (ws_size >= need_part) ? 1 : 0;

  pre_kernel<<<dim3(1024), dim3(256), 0, stream>>>(x, y, xs, ys, x2h, y2h,
                                                   rowmax_u, colmax_u, out,
                                                   use_part);
  main_kernel<<<dim3(1024), dim3(256), 0, stream>>>(xs, ys, x2h, y2h,
                                                    rowpart, colpart,
                                                    rowmax_u, colmax_u,
                                                    use_part);
  reduce_kernel<<<dim3(256), dim3(256), 0, stream>>>(rowpart, colpart,
                                                     rowmax_u, colmax_u, y2h,
                                                     out, use_part);
}